// Round 1
// baseline (837.494 us; speedup 1.0000x reference)
//
#include <hip/hip_runtime.h>
#include <math.h>

#define D_MODEL 512
#define N_LAYERS 4
#define LATENT 1024
#define D_INNER 1024
#define D_STATE 16
#define DT_RANK 32
#define KCONV 4
#define BATCH 4
#define SEQ 1024
#define NTOK (BATCH * SEQ) /* 4096 */
#define PCH 32
#define CLEN 32
#define NCAT 1152  /* merged xproj+dt GEMM N: 1024 dt | 32 B/C | 96 pad */

typedef __attribute__((ext_vector_type(8))) short short8;
typedef __attribute__((ext_vector_type(4))) float floatx4;
typedef unsigned short ushort_t;

// gfx9 s_waitcnt immediates: vmcnt lo[3:0] hi[15:14], expcnt[6:4], lgkm[11:8]
#define WC_VM0   0x0F70  /* vmcnt(0), lgkm/exp free */
#define WC_LGKM0 0xC07F  /* lgkmcnt(0), vm/exp free */

__device__ __forceinline__ ushort_t f2bf(float f) {
    union { float f; unsigned u; } v; v.f = f;
    unsigned r = v.u + 0x7FFFu + ((v.u >> 16) & 1u);  // RNE
    return (ushort_t)(r >> 16);
}
__device__ __forceinline__ float bf2f(ushort_t u) {
    union { unsigned u; float f; } v; v.u = ((unsigned)u) << 16;
    return v.f;
}
// async global -> LDS, 16B per lane (verified width=16 on gfx950, m97).
__device__ __forceinline__ void gll16(const void* g, void* l) {
    __builtin_amdgcn_global_load_lds(
        (const __attribute__((address_space(1))) void*)g,
        (__attribute__((address_space(3))) void*)l, 16, 0, 0);
}

// ---------------------------------------------------------------------------
// bf16 MFMA GEMM: C[M,N] = A[M,K](bf16) @ Bt[N,K](bf16)^T (+bias)(+C)
// flags: 1 = add bias[n], 2 = accumulate into C (fp32),
//        4 = merged-dt epilogue: n<1024 -> v = softplus(v + bias[n]),
//        8 = write bf16 output to Cb instead of fp32 C.
//
// Tile BM=128 x BN (64 or 128), BK=64, 256 threads / 4 waves (2x2).
// Per-wave output 64 x BN/2 via 4xNJ 16x16 fragments -> fragment reuse 4
// (m93 rung of the ladder: reuse 2 -> 4 moves LDS bytes/MFMA from 1KB to
// 0.5KB, under the 4.8cyc MFMA issue cost). Double-buffered LDS with
// counted vmcnt (loads for tile t+1 stay in flight across the barrier).
//
// LDS layout: full rows [row][64] bf16 (row stride 128B) with XOR-8 chunk
// swizzle: LDS[r][c] holds global chunk c^(r&7). DMA dest stays LINEAR
// (wave-uniform base + lane*16B, required m104/m108); the permutation is
// applied on the per-lane GLOBAL source address and undone on the
// ds_read_b128 side (m173/m201 both-sides-or-neither rule). Each
// quarter-wave of a frag read then covers all 8 16B bank groups ->
// conflict-free (was ~4 extra cycles/read at the old [ks][row][32]).
// ---------------------------------------------------------------------------
template<int BN>
__global__ __launch_bounds__(256, (BN == 64) ? 3 : 2) void gemm_bf16_tile(
    const ushort_t* __restrict__ A, int lda,
    const ushort_t* __restrict__ Bt, int ldb,
    float* __restrict__ C, ushort_t* __restrict__ Cb, int ldc,
    const float* __restrict__ bias,
    int M, int N, int K, int flags)
{
    constexpr int BM = 128;
    constexpr int NJ = BN / 32;        // per-wave B fragments
    constexpr int AOPS = 4;            // 128x64x2B / (256 lanes * 16B)
    constexpr int BOPS = BN / 32;
    constexpr int NOPS = AOPS + BOPS;  // 6 or 8, fits vmcnt lo bits [3:0]
    constexpr int WC_PREF = 0x0F70 | NOPS;

    __shared__ ushort_t As[2][BM * 64];   // 32 KB
    __shared__ ushort_t Bs[2][BN * 64];   // 16/32 KB

    const int tid = threadIdx.x;
    const int m0 = blockIdx.y * BM;
    const int n0 = blockIdx.x * BN;
    const int w = tid >> 6;
    const int lane = tid & 63;
    const int quad = lane >> 4;
    const int l16 = lane & 15;
    const int wm = (w & 1) * 64;
    const int wn = (w >> 1) * (BN / 2);

    // staging: op q covers rows q*32..q*32+31. Thread tid: row (tid>>3) of
    // the slab, LDS chunk (tid&7); fetches global chunk (tid&7)^(row&7).
    // (q*32 == 0 mod 8, so row&7 is slab-row&7.)
    const int srow = tid >> 3;
    const int schunk = ((tid & 7) ^ (srow & 7)) * 8;
    const ushort_t* ga = A + (size_t)(m0 + srow) * lda + schunk;
    const ushort_t* gb = Bt + (size_t)(n0 + srow) * ldb + schunk;
    const int lofs = tid * 8;  // linear LDS dest (elements)

    // read-side swizzle: frag row r = 16*k + l16 -> r&7 = l16&7;
    // global chunk (ks*4+quad) lives at LDS chunk (ks*4+quad)^(l16&7).
    const int swz0 = ((0 * 4 + quad) ^ (l16 & 7)) * 8;
    const int swz1 = ((1 * 4 + quad) ^ (l16 & 7)) * 8;

    floatx4 acc[4][NJ] = {};
    const int nt = K >> 6;

    // prologue: tile 0 -> buf 0 (NOPS outstanding)
    #pragma unroll
    for (int q = 0; q < AOPS; q++)
        gll16(ga + (size_t)q * 32 * lda, &As[0][q * 2048 + lofs]);
    #pragma unroll
    for (int q = 0; q < BOPS; q++)
        gll16(gb + (size_t)q * 32 * ldb, &Bs[0][q * 2048 + lofs]);

    for (int kt = 0; kt < nt; kt++) {
        const int cur = kt & 1;
        if (kt + 1 < nt) {
            const ushort_t* pa = ga + (kt + 1) * 64;
            const ushort_t* pb = gb + (kt + 1) * 64;
            #pragma unroll
            for (int q = 0; q < AOPS; q++)
                gll16(pa + (size_t)q * 32 * lda, &As[1 - cur][q * 2048 + lofs]);
            #pragma unroll
            for (int q = 0; q < BOPS; q++)
                gll16(pb + (size_t)q * 32 * ldb, &Bs[1 - cur][q * 2048 + lofs]);
            __builtin_amdgcn_s_waitcnt(WC_PREF);  // tile kt landed; NOPS newer in flight
        } else {
            __builtin_amdgcn_s_waitcnt(WC_VM0);
        }
        __builtin_amdgcn_s_barrier();

        short8 af[2][4], bfr[2][NJ];
        #pragma unroll
        for (int i = 0; i < 4; i++) {
            const int r = wm + i * 16 + l16;
            af[0][i] = *(const short8*)&As[cur][r * 64 + swz0];
            af[1][i] = *(const short8*)&As[cur][r * 64 + swz1];
        }
        #pragma unroll
        for (int j = 0; j < NJ; j++) {
            const int r = wn + j * 16 + l16;
            bfr[0][j] = *(const short8*)&Bs[cur][r * 64 + swz0];
            bfr[1][j] = *(const short8*)&Bs[cur][r * 64 + swz1];
        }
        __builtin_amdgcn_s_waitcnt(WC_LGKM0);    // my LDS reads complete
        __builtin_amdgcn_s_barrier();            // everyone's complete -> buf reusable

        #pragma unroll
        for (int ks = 0; ks < 2; ks++)
            #pragma unroll
            for (int i = 0; i < 4; i++)
                #pragma unroll
                for (int j = 0; j < NJ; j++)
                    acc[i][j] = __builtin_amdgcn_mfma_f32_16x16x32_bf16(
                        af[ks][i], bfr[ks][j], acc[i][j], 0, 0, 0);
    }

    // C/D layout (m89-verified): col = lane&15, row = quad*4 + reg.
    #pragma unroll
    for (int j = 0; j < NJ; j++) {
        int n = n0 + wn + j * 16 + l16;
        float bv = (flags & 1) ? bias[n] : 0.f;
        bool do_sp = (flags & 4) && (n < 1024);
        float spb = do_sp ? bias[n] : 0.f;
        #pragma unroll
        for (int i = 0; i < 4; i++) {
            int mrow = m0 + wm + i * 16 + quad * 4;
            #pragma unroll
            for (int rr = 0; rr < 4; rr++) {
                size_t idx = (size_t)(mrow + rr) * ldc + n;
                float v = acc[i][j][rr] + bv;
                if (do_sp) {
                    v += spb;
                    v = (v > 20.f) ? v : log1pf(__expf(v));
                }
                if (flags & 8) {
                    Cb[idx] = f2bf(v);
                } else {
                    if (flags & 2) v += C[idx];
                    C[idx] = v;
                }
            }
        }
    }
}

// ---------------------------------------------------------------------------
// build_wdt: Wcat rows 0..1023 = (xw[:, :32] @ dt_w)^T, bf16 [n][k].
// ---------------------------------------------------------------------------
__global__ __launch_bounds__(256) void build_wdt_kernel(
    const float* __restrict__ xproj_w, const float* __restrict__ dt_w,
    ushort_t* __restrict__ wcat)
{
    const int l = blockIdx.z;
    const int n0 = blockIdx.x * 64;
    const int k0 = blockIdx.y * 64;
    const float* xw  = xproj_w + (size_t)l * D_INNER * 64;
    const float* dtw = dt_w + (size_t)l * DT_RANK * D_INNER;

    __shared__ float xs[64][33];   // [k][r]
    __shared__ float ds[32][65];   // [r][n]

    const int tid = threadIdx.x;
    {
        int row = tid >> 2;
        int col = (tid & 3) * 8;
        #pragma unroll
        for (int q = 0; q < 8; q++)
            xs[row][col + q] = xw[(size_t)(k0 + row) * 64 + col + q];
    }
    {
        int row = tid >> 3;
        int col = (tid & 7) * 8;
        #pragma unroll
        for (int q = 0; q < 8; q++)
            ds[row][col + q] = dtw[(size_t)row * D_INNER + n0 + col + q];
    }
    __syncthreads();

    const int ty = tid & 15;
    const int tx = tid >> 4;
    float acc[4][4] = {};
    #pragma unroll
    for (int r = 0; r < 32; r++) {
        float a[4], b[4];
        #pragma unroll
        for (int i = 0; i < 4; i++) a[i] = xs[ty * 4 + i][r];
        #pragma unroll
        for (int j = 0; j < 4; j++) b[j] = ds[r][tx * 4 + j];
        #pragma unroll
        for (int j = 0; j < 4; j++)
            #pragma unroll
            for (int i = 0; i < 4; i++)
                acc[j][i] = fmaf(a[i], b[j], acc[j][i]);
    }
    #pragma unroll
    for (int j = 0; j < 4; j++) {
        int n = n0 + tx * 4 + j;
        ushort4 o;
        o.x = f2bf(acc[j][0]); o.y = f2bf(acc[j][1]);
        o.z = f2bf(acc[j][2]); o.w = f2bf(acc[j][3]);
        *(ushort4*)&wcat[((size_t)l * NCAT + n) * D_INNER + k0 + ty * 4] = o;
    }
}

// ---------------------------------------------------------------------------
// build_wbc: Wcat rows 1024..1151: j<32 -> xw[k][32+j] cast; else zero pad.
// (Pad MUST be written every launch: d_ws is re-poisoned to 0xAA.)
// ---------------------------------------------------------------------------
__global__ __launch_bounds__(256) void build_wbc_kernel(
    const float* __restrict__ xproj_w, ushort_t* __restrict__ wcat)
{
    const int idx = blockIdx.x * 256 + threadIdx.x;
    const int k = idx & 1023;
    const int j = (idx >> 10) & 127;
    const int l = idx >> 17;
    ushort_t v = 0;
    if (j < 32)
        v = f2bf(xproj_w[((size_t)l * D_INNER + k) * 64 + 32 + j]);
    wcat[((size_t)l * NCAT + 1024 + j) * D_INNER + k] = v;
}

// ---------------------------------------------------------------------------
__global__ __launch_bounds__(256) void transpose_cast_kernel(
    const float* __restrict__ in, ushort_t* __restrict__ out, int K, int N)
{
    __shared__ float tile[32][33];
    const int n0 = blockIdx.x * 32, k0 = blockIdx.y * 32;
    const int tx = threadIdx.x & 31, ty = threadIdx.x >> 5;
    #pragma unroll
    for (int i = 0; i < 4; i++)
        tile[ty + i * 8][tx] = in[(size_t)(k0 + ty + i * 8) * N + n0 + tx];
    __syncthreads();
    #pragma unroll
    for (int i = 0; i < 4; i++)
        out[(size_t)(n0 + ty + i * 8) * K + k0 + tx] = f2bf(tile[tx][ty + i * 8]);
}

// ---------------------------------------------------------------------------
__global__ __launch_bounds__(256) void cast_bf16_kernel(
    const float* __restrict__ in, ushort_t* __restrict__ out)
{
    const int i = blockIdx.x * 256 + threadIdx.x;
    out[i] = f2bf(in[i]);
}

// ---------------------------------------------------------------------------
__global__ __launch_bounds__(256) void rmsnorm_kernel(
    const float* __restrict__ x, const float* __restrict__ w,
    ushort_t* __restrict__ y)
{
    const int row = blockIdx.x;
    const float* xr = x + (size_t)row * D_MODEL;
    ushort_t* yr = y + (size_t)row * D_MODEL;
    const int tid = threadIdx.x;

    float v0 = xr[tid], v1 = xr[tid + 256];
    float ss = v0 * v0 + v1 * v1;
    #pragma unroll
    for (int off = 32; off > 0; off >>= 1) ss += __shfl_down(ss, off);

    __shared__ float wsum[4];
    __shared__ float scale_s;
    int wid = tid >> 6, lane = tid & 63;
    if (lane == 0) wsum[wid] = ss;
    __syncthreads();
    if (tid == 0) {
        float tot = wsum[0] + wsum[1] + wsum[2] + wsum[3];
        scale_s = 1.0f / sqrtf(tot / (float)D_MODEL + 1e-5f);
    }
    __syncthreads();
    float sc = scale_s;
    yr[tid] = f2bf(v0 * sc * w[tid]);
    yr[tid + 256] = f2bf(v1 * sc * w[tid + 256]);
}

// ---------------------------------------------------------------------------
// Causal dwconv (K=4) + bias + silu. Reads bf16 xz (stride 2048, xp plane),
// writes bf16 u.
// ---------------------------------------------------------------------------
__global__ __launch_bounds__(256) void conv_silu_kernel(
    const ushort_t* __restrict__ xz, const float* __restrict__ w,
    const float* __restrict__ bconv, ushort_t* __restrict__ outb)
{
    const int idx = blockIdx.x * 256 + threadIdx.x;
    const int d = idx & (D_INNER - 1);
    const int t = (idx >> 10) & (SEQ - 1);
    const int row = idx >> 10;
    const ushort_t* base = xz + (size_t)row * 2048 + d;

    float s = 0.f;
    #pragma unroll
    for (int k = 0; k < KCONV; k++) {
        int tt = t + k - (KCONV - 1);
        if (tt >= 0)
            s = fmaf(bf2f(base[(ptrdiff_t)(k - (KCONV - 1)) * 2048]), w[d * KCONV + k], s);
    }
    s += bconv[d];
    float r = s / (1.f + __expf(-s));
    outb[idx] = f2bf(r);
}

// ---------------------------------------------------------------------------
// Chunked selective scan (3 passes), CLEN=32. dt/B/C in dbl (stride NCAT):
// dbl[row][d]=softplus'ed dt; dbl[row][1024+n]=B[n]; dbl[row][1040+n]=C[n].
// u is bf16 in xb; z is bf16 in xz[:,1024:].
// ---------------------------------------------------------------------------
__global__ __launch_bounds__(256) void scan_pass1(
    const float* __restrict__ dbl, const ushort_t* __restrict__ ub,
    const float* __restrict__ A_log,
    float* __restrict__ hfin, float* __restrict__ sumdt)
{
    const int tid = threadIdx.x;
    const int b = blockIdx.x >> 7;
    const int p = (blockIdx.x >> 2) & 31;
    const int d = ((blockIdx.x & 3) << 8) + tid;
    const int t0 = p * CLEN;

    float A[D_STATE];
    #pragma unroll
    for (int n = 0; n < D_STATE; n++) A[n] = -expf(A_log[d * D_STATE + n]);

    float h[D_STATE] = {};
    float sdt = 0.f;

    const float* dtp = dbl + ((size_t)b * SEQ + t0) * NCAT + d;
    const float* bp  = dbl + ((size_t)b * SEQ + t0) * NCAT + 1024;
    const ushort_t* up = ub + ((size_t)b * SEQ + t0) * D_INNER + d;

    for (int t = 0; t < CLEN; t++) {
        float dtv = dtp[(size_t)t * NCAT];
        float uv  = bf2f(up[(size_t)t * D_INNER]);
        float dtu = dtv * uv;
        sdt += dtv;
        #pragma unroll
        for (int n = 0; n < D_STATE; n++)
            h[n] = fmaf(__expf(dtv * A[n]), h[n], dtu * bp[t * NCAT + n]);
    }

    size_t base = (size_t)(b * PCH + p) * D_STATE * D_INNER + d;
    #pragma unroll
    for (int n = 0; n < D_STATE; n++) hfin[base + (size_t)n * D_INNER] = h[n];
    sumdt[(size_t)(b * PCH + p) * D_INNER + d] = sdt;
}

__global__ __launch_bounds__(256) void scan_pass2(
    const float* __restrict__ A_log, const float* __restrict__ sumdt,
    float* __restrict__ hc)
{
    const int tid = threadIdx.x;
    const int b = blockIdx.x >> 6;
    const int n = (blockIdx.x >> 2) & 15;
    const int d = ((blockIdx.x & 3) << 8) + tid;

    const float Aval = -expf(A_log[d * D_STATE + n]);
    float h = 0.f;
    for (int p = 0; p < PCH; p++) {
        size_t idx = ((size_t)(b * PCH + p) * D_STATE + n) * D_INNER + d;
        float fin = hc[idx];
        hc[idx] = h;
        h = fmaf(__expf(Aval * sumdt[(size_t)(b * PCH + p) * D_INNER + d]), h, fin);
    }
}

// pass3: u (bf16, in ub) read then overwritten IN PLACE with y*silu(z).
__global__ __launch_bounds__(256) void scan_pass3(
    const float* __restrict__ dbl, const ushort_t* __restrict__ xz,
    const float* __restrict__ A_log, const float* __restrict__ Dp,
    const float* __restrict__ hstart, ushort_t* ub)
{
    const int tid = threadIdx.x;
    const int b = blockIdx.x >> 7;
    const int p = (blockIdx.x >> 2) & 31;
    const int d = ((blockIdx.x & 3) << 8) + tid;
    const int t0 = p * CLEN;

    float A[D_STATE];
    #pragma unroll
    for (int n = 0; n < D_STATE; n++) A[n] = -expf(A_log[d * D_STATE + n]);
    const float Dv = Dp[d];

    float h[D_STATE];
    size_t base = (size_t)(b * PCH + p) * D_STATE * D_INNER + d;
    #pragma unroll
    for (int n = 0; n < D_STATE; n++) h[n] = hstart[base + (size_t)n * D_INNER];

    const float* dtp = dbl + ((size_t)b * SEQ + t0) * NCAT + d;
    const float* bp  = dbl + ((size_t)b * SEQ + t0) * NCAT + 1024;
    const ushort_t* zp = xz + ((size_t)b * SEQ + t0) * 2048 + 1024 + d;
    ushort_t* up = ub + ((size_t)b * SEQ + t0) * D_INNER + d;

    for (int t = 0; t < CLEN; t++) {
        float dtv = dtp[(size_t)t * NCAT];
        float uv  = bf2f(up[(size_t)t * D_INNER]);
        float zv  = bf2f(zp[(size_t)t * 2048]);
        float dtu = dtv * uv;
        float y = 0.f;
        #pragma unroll
        for (int n = 0; n < D_STATE; n++) {
            h[n] = fmaf(__expf(dtv * A[n]), h[n], dtu * bp[t * NCAT + n]);
            y = fmaf(h[n], bp[t * NCAT + 16 + n], y);
        }
        float res = fmaf(uv, Dv, y);
        res *= zv / (1.f + __expf(-zv));
        up[(size_t)t * D_INNER] = f2bf(res);
    }
}

// ---------------------------------------------------------------------------
__global__ __launch_bounds__(256) void softmax_kernel(
    const float* __restrict__ in, float* __restrict__ out)
{
    const int idx = blockIdx.x * 256 + threadIdx.x;
    float v = in[idx];
    float m = v;
    #pragma unroll
    for (int off = 16; off > 0; off >>= 1) m = fmaxf(m, __shfl_xor(m, off, 32));
    float e = expf(v - m);
    float s = e;
    #pragma unroll
    for (int off = 16; off > 0; off >>= 1) s += __shfl_xor(s, off, 32);
    out[idx] = e / s;
}

// ---------------------------------------------------------------------------
extern "C" void kernel_launch(void* const* d_in, const int* in_sizes, int n_in,
                              void* d_out, int out_size, void* d_ws, size_t ws_size,
                              hipStream_t stream)
{
    const float* x       = (const float*)d_in[0];
    const float* lin1_w  = (const float*)d_in[1];
    const float* lin1_b  = (const float*)d_in[2];
    const float* norm_w  = (const float*)d_in[3];
    const float* in_w    = (const float*)d_in[4];
    const float* conv_w  = (const float*)d_in[5];
    const float* conv_b  = (const float*)d_in[6];
    const float* xproj_w = (const float*)d_in[7];
    const float* dt_w    = (const float*)d_in[8];
    const float* dt_b    = (const float*)d_in[9];
    const float* A_log   = (const float*)d_in[10];
    const float* Dp      = (const float*)d_in[11];
    const float* out_w   = (const float*)d_in[12];
    const float* lin2_w  = (const float*)d_in[13];
    const float* lin2_b  = (const float*)d_in[14];
    float* outp = (float*)d_out;
    (void)ws_size; (void)in_sizes; (void)n_in; (void)out_size;

    float* ws = (float*)d_ws;
    const size_t F1M = 1u << 20;
    float* h     = ws;                        // 2M fl
    float* dbl   = h + 2 * F1M;               // 4.5M fl (also lin2 logits)
    float* sumdt = dbl + (size_t)NTOK * NCAT; // 128K fl
    float* hfin  = sumdt + (size_t)BATCH * PCH * D_INNER; // 2M fl
    ushort_t* xzb   = (ushort_t*)(hfin + 2 * F1M);        // 8M us (xp|z, 2048)
    ushort_t* hn_bf = xzb + 8 * F1M;                      // 2M us
    ushort_t* xb    = hn_bf + 2 * F1M;                    // 4M us
    ushort_t* lin1_wt = xb + 4 * F1M;                     // 512*1024
    ushort_t* in_wt   = lin1_wt + (size_t)512 * 1024;     // 4*2048*512
    ushort_t* out_wt  = in_wt + (size_t)4 * 2048 * 512;   // 4*512*1024
    ushort_t* lin2_wt = out_wt + (size_t)4 * 512 * 1024;  // 1024*512
    ushort_t* wcat    = lin2_wt + (size_t)1024 * 512;     // 4*1152*1024

    dim3 blk(256);

    // --- weight prep ---
    transpose_cast_kernel<<<dim3(512 / 32, 1024 / 32), blk, 0, stream>>>(
        lin1_w, lin1_wt, LATENT, D_MODEL);
    for (int l = 0; l < N_LAYERS; l++) {
        transpose_cast_kernel<<<dim3(2048 / 32, 512 / 32), blk, 0, stream>>>(
            in_w + (size_t)l * 512 * 2048, in_wt + (size_t)l * 2048 * 512, 512, 2048);
        transpose_cast_kernel<<<dim3(512 / 32, 1024 / 32), blk, 0, stream>>>(
            out_w + (size_t)l * 1024 * 512, out_wt + (size_t)l * 512 * 1024, 1024, 512);
    }
    transpose_cast_kernel<<<dim3(1024 / 32, 512 / 32), blk, 0, stream>>>(
        lin2_w, lin2_wt, D_MODEL, LATENT);
    build_wdt_kernel<<<dim3(16, 16, N_LAYERS), blk, 0, stream>>>(
        xproj_w, dt_w, wcat);
    build_wbc_kernel<<<dim3((N_LAYERS * 128 * 1024) / 256), blk, 0, stream>>>(
        xproj_w, wcat);

    // x -> bf16
    cast_bf16_kernel<<<dim3((NTOK * LATENT) / 256), blk, 0, stream>>>(x, xb);

    // lin1: h = x_bf @ lin1_wt^T + b  (fp32 out), grid 8x32 = 256 blocks
    gemm_bf16_tile<64><<<dim3(D_MODEL / 64, NTOK / 128), blk, 0, stream>>>(
        xb, LATENT, lin1_wt, LATENT, h, nullptr, D_MODEL, lin1_b,
        NTOK, D_MODEL, LATENT, 1);

    for (int l = 0; l < N_LAYERS; l++) {
        const float* nw = norm_w + (size_t)l * D_MODEL;
        const float* cw = conv_w + (size_t)l * D_INNER * KCONV;
        const float* cb = conv_b + (size_t)l * D_INNER;
        const float* db = dt_b + (size_t)l * D_INNER;
        const float* al = A_log + (size_t)l * D_INNER * D_STATE;
        const float* dp = Dp + (size_t)l * D_INNER;
        const ushort_t* iwt = in_wt + (size_t)l * 2048 * 512;
        const ushort_t* owt = out_wt + (size_t)l * 512 * 1024;
        const ushort_t* wc  = wcat + (size_t)l * NCAT * D_INNER;

        rmsnorm_kernel<<<dim3(NTOK), blk, 0, stream>>>(h, nw, hn_bf);

        // fused in-proj: xzb = hn @ in_w[l]  (N=2048, bf16 out, 16x32=512 blocks)
        gemm_bf16_tile<128><<<dim3(2048 / 128, NTOK / 128), blk, 0, stream>>>(
            hn_bf, D_MODEL, iwt, D_MODEL, nullptr, xzb, 2048, nullptr,
            NTOK, 2048, D_MODEL, 8);

        // conv + silu: xzb[:, :1024] -> xb (bf16 u)
        conv_silu_kernel<<<dim3((NTOK * D_INNER) / 256), blk, 0, stream>>>(
            xzb, cw, cb, xb);

        // merged xproj+dt GEMM: dbl[:, :1024]=softplus(u@Wdt+dt_b),
        //                       dbl[:, 1024:1056]=B|C   (fp32 out, 18x32=576 blocks)
        gemm_bf16_tile<64><<<dim3(NCAT / 64, NTOK / 128), blk, 0, stream>>>(
            xb, D_INNER, wc, D_INNER, dbl, nullptr, NCAT, db,
            NTOK, NCAT, D_INNER, 4);

        // chunked scan; pass3 overwrites xb in place with y*silu(z)
        scan_pass1<<<dim3(BATCH * PCH * (D_INNER / 256)), blk, 0, stream>>>(
            dbl, xb, al, hfin, sumdt);
        scan_pass2<<<dim3(BATCH * D_STATE * (D_INNER / 256)), blk, 0, stream>>>(
            al, sumdt, hfin);
        scan_pass3<<<dim3(BATCH * PCH * (D_INNER / 256)), blk, 0, stream>>>(
            dbl, xzb, al, dp, hfin, xb);

        // h += y_bf @ out_wt^T  (fp32 accumulate, 8x32=256 blocks)
        gemm_bf16_tile<64><<<dim3(D_MODEL / 64, NTOK / 128), blk, 0, stream>>>(
            xb, D_INNER, owt, D_INNER, h, nullptr, D_MODEL, nullptr,
            NTOK, D_MODEL, D_INNER, 2);
    }

    // h -> bf16, lin2 (logits into dbl), softmax
    cast_bf16_kernel<<<dim3((NTOK * D_MODEL) / 256), blk, 0, stream>>>(h, xb);
    gemm_bf16_tile<64><<<dim3(LATENT / 64, NTOK / 128), blk, 0, stream>>>(
        xb, D_MODEL, lin2_wt, D_MODEL, dbl, nullptr, LATENT, lin2_b,
        NTOK, LATENT, D_MODEL, 1);
    softmax_kernel<<<dim3((NTOK * LATENT) / 256), blk, 0, stream>>>(dbl, outp);
}

// Round 3
// 782.780 us; speedup vs baseline: 1.0699x; 1.0699x over previous
//
#include <hip/hip_runtime.h>
#include <math.h>

#define D_MODEL 512
#define N_LAYERS 4
#define LATENT 1024
#define D_INNER 1024
#define D_STATE 16
#define DT_RANK 32
#define KCONV 4
#define BATCH 4
#define SEQ 1024
#define NTOK (BATCH * SEQ) /* 4096 */
#define PCH 32
#define CLEN 32
#define NCAT 1152  /* merged xproj+dt GEMM N: 1024 dt | 32 B/C | 96 pad */

typedef __attribute__((ext_vector_type(8))) short short8;
typedef __attribute__((ext_vector_type(4))) float floatx4;
typedef unsigned short ushort_t;

// gfx9 s_waitcnt immediates: vmcnt lo[3:0] hi[15:14], expcnt[6:4], lgkm[11:8]
#define WC_VM4   0x0F74  /* vmcnt(4), lgkm/exp free */
#define WC_VM0   0x0F70  /* vmcnt(0) */
#define WC_LGKM0 0xC07F  /* lgkmcnt(0), vm/exp free */

__device__ __forceinline__ ushort_t f2bf(float f) {
    union { float f; unsigned u; } v; v.f = f;
    unsigned r = v.u + 0x7FFFu + ((v.u >> 16) & 1u);  // RNE
    return (ushort_t)(r >> 16);
}
__device__ __forceinline__ float bf2f(ushort_t u) {
    union { unsigned u; float f; } v; v.u = ((unsigned)u) << 16;
    return v.f;
}
// async global -> LDS, 16B per lane (verified width=16 on gfx950, m97).
__device__ __forceinline__ void gll16(const void* g, void* l) {
    __builtin_amdgcn_global_load_lds(
        (const __attribute__((address_space(1))) void*)g,
        (__attribute__((address_space(3))) void*)l, 16, 0, 0);
}

// ---------------------------------------------------------------------------
// bf16 MFMA GEMM: C[M,N] = A[M,K](bf16) @ Bt[N,K](bf16)^T (+bias)(+C)
// flags: 1 = add bias[n], 2 = accumulate into C (fp32),
//        4 = merged-dt epilogue: n<1024 -> v = softplus(v + bias[n]),
//        8 = write bf16 output to Cb instead of fp32 C.
//
// 64x64 tile, BK=64, 256 threads / 4 waves (2x2), wave = 32x32 via 2x2
// 16x16x32 fragments over 2 k-slices.
//
// Structure (r2, resubmitted after infra failure, + sched_barrier pins):
//  * TRIPLE-buffered LDS, prefetch distance 2: tile k issued at iter k-2
//    -> ~2 iterations (>=600 cyc) for global_load_lds to land (HBM miss
//    ~900 cyc, m126; L2 hit ~200-300).
//  * ONE barrier per iteration: each wave reaches the top-of-loop barrier
//    only after its lgkmcnt(0) of the previous iteration, so the buffer
//    this iteration's DMA targets ((k+2)%3 == (k-1)%3, read last iter)
//    is provably drained by ALL waves.
//  * sched_barrier(0) after the barrier and after the lgkm wait: raw
//    s_barrier is NOT a compiler fence for side-effect-free LDS loads
//    (rule #18 hoisting hazard) — pin ds_reads after the DMA-landed
//    point and MFMAs after the reads. Zero-cost: positions are ones the
//    schedule must respect anyway (not the m141 over-pinning mode).
//  * Bijective XCD-chunked block swizzle (m204): consecutive block ids
//    (same A m-panel) stay on one XCD's L2 -> kills the measured 3.7x
//    A-panel HBM over-fetch (37.6 MB vs 10.25 ideal); in-loop DMAs become
//    L2 hits, inside the 2-iter slack. All grids have nwg % 8 == 0.
// LDS 48 KB -> 3 blocks/CU (12 waves/CU) for cross-block stall cover.
// XOR-8 chunk swizzle on LDS (r1, verified: bank conflicts 2.36M -> 0):
// linear DMA dest + pre-swizzled global src + swizzled ds_read.
// ---------------------------------------------------------------------------
__global__ __launch_bounds__(256, 3) void gemm_bf16_tile(
    const ushort_t* __restrict__ A, int lda,
    const ushort_t* __restrict__ Bt, int ldb,
    float* __restrict__ C, ushort_t* __restrict__ Cb, int ldc,
    const float* __restrict__ bias,
    int M, int N, int K, int flags)
{
    __shared__ ushort_t As[3][4096];   // 3 x 8 KB
    __shared__ ushort_t Bs[3][4096];   // 3 x 8 KB

    // XCD-chunked bijective remap: HW block orig lands on XCD orig&7;
    // give XCD k a contiguous work range -> whole m-panels per XCD.
    const int gx = gridDim.x;
    const int nwg = gx * gridDim.y;
    const int orig = blockIdx.y * gx + blockIdx.x;
    const int qq = nwg >> 3, rr = nwg & 7;
    const int xcd = orig & 7, loc = orig >> 3;
    const int swz = (xcd < rr ? xcd * (qq + 1) : rr * (qq + 1) + (xcd - rr) * qq) + loc;
    const int m0 = (swz / gx) * 64;
    const int n0 = (swz % gx) * 64;

    const int tid = threadIdx.x;
    const int w = tid >> 6;
    const int lane = tid & 63;
    const int quad = lane >> 4;
    const int l16 = lane & 15;
    const int wm = (w & 1) * 32;
    const int wn = (w >> 1) * 32;

    // staging: thread tid -> slab row (tid>>3) (0..31), LDS chunk (tid&7);
    // fetches global chunk (tid&7)^(row&7). Two 32-row slabs per matrix.
    const int srow = tid >> 3;
    const int schunk = ((tid & 7) ^ (srow & 7)) * 8;
    const ushort_t* ga = A + (size_t)(m0 + srow) * lda + schunk;
    const ushort_t* gb = Bt + (size_t)(n0 + srow) * ldb + schunk;
    const int lofs = tid * 8;  // linear LDS dest (elements)

    // read-side swizzle: frag row r -> r&7 = l16&7; global chunk
    // (ks*4+quad) lives at LDS chunk (ks*4+quad)^(l16&7).
    const int swz0 = ((0 * 4 + quad) ^ (l16 & 7)) * 8;
    const int swz1 = ((1 * 4 + quad) ^ (l16 & 7)) * 8;

    floatx4 acc[2][2] = {};
    const int nt = K >> 6;

    // 4 VMEM instrs per wave per tile.
    #define STAGE(t, b)                                         \
        do {                                                    \
            const ushort_t* pa_ = ga + (t) * 64;                \
            const ushort_t* pb_ = gb + (t) * 64;                \
            gll16(pa_, &As[(b)][lofs]);                         \
            gll16(pa_ + (size_t)32 * lda, &As[(b)][2048 + lofs]); \
            gll16(pb_, &Bs[(b)][lofs]);                         \
            gll16(pb_ + (size_t)32 * ldb, &Bs[(b)][2048 + lofs]); \
        } while (0)

    // prologue: tiles 0,1 in flight (distance 2)
    STAGE(0, 0);
    if (nt > 1) STAGE(1, 1);

    int cur = 0;
    for (int kt = 0; kt < nt; kt++) {
        // tile kt landed (issued at kt-2); tile kt+1 (4 ops) stays in flight
        if (kt + 1 < nt) __builtin_amdgcn_s_waitcnt(WC_VM4);
        else             __builtin_amdgcn_s_waitcnt(WC_VM0);
        __builtin_amdgcn_s_barrier();
        __builtin_amdgcn_sched_barrier(0);  // no LDS read hoists above this

        if (kt + 2 < nt) {
            int nb = cur + 2; if (nb >= 3) nb -= 3;
            STAGE(kt + 2, nb);
        }

        short8 af[2][2], bfr[2][2];
        #pragma unroll
        for (int i = 0; i < 2; i++) {
            const int r = wm + i * 16 + l16;
            af[0][i] = *(const short8*)&As[cur][r * 64 + swz0];
            af[1][i] = *(const short8*)&As[cur][r * 64 + swz1];
        }
        #pragma unroll
        for (int j = 0; j < 2; j++) {
            const int r = wn + j * 16 + l16;
            bfr[0][j] = *(const short8*)&Bs[cur][r * 64 + swz0];
            bfr[1][j] = *(const short8*)&Bs[cur][r * 64 + swz1];
        }
        __builtin_amdgcn_s_waitcnt(WC_LGKM0);  // my ds_reads complete
        __builtin_amdgcn_sched_barrier(0);     // MFMAs stay below the wait

        #pragma unroll
        for (int ks = 0; ks < 2; ks++)
            #pragma unroll
            for (int i = 0; i < 2; i++)
                #pragma unroll
                for (int j = 0; j < 2; j++)
                    acc[i][j] = __builtin_amdgcn_mfma_f32_16x16x32_bf16(
                        af[ks][i], bfr[ks][j], acc[i][j], 0, 0, 0);

        cur++; if (cur == 3) cur = 0;
    }
    #undef STAGE

    // C/D layout (m89-verified): col = lane&15, row = quad*4 + reg.
    #pragma unroll
    for (int j = 0; j < 2; j++) {
        int n = n0 + wn + j * 16 + l16;
        float bv = (flags & 1) ? bias[n] : 0.f;
        bool do_sp = (flags & 4) && (n < 1024);
        float spb = do_sp ? bias[n] : 0.f;
        #pragma unroll
        for (int i = 0; i < 2; i++) {
            int mrow = m0 + wm + i * 16 + quad * 4;
            #pragma unroll
            for (int rr2 = 0; rr2 < 4; rr2++) {
                size_t idx = (size_t)(mrow + rr2) * ldc + n;
                float v = acc[i][j][rr2] + bv;
                if (do_sp) {
                    v += spb;
                    v = (v > 20.f) ? v : log1pf(__expf(v));
                }
                if (flags & 8) {
                    Cb[idx] = f2bf(v);
                } else {
                    if (flags & 2) v += C[idx];
                    C[idx] = v;
                }
            }
        }
    }
}

// ---------------------------------------------------------------------------
// build_wdt: Wcat rows 0..1023 = (xw[:, :32] @ dt_w)^T, bf16 [n][k].
// ---------------------------------------------------------------------------
__global__ __launch_bounds__(256) void build_wdt_kernel(
    const float* __restrict__ xproj_w, const float* __restrict__ dt_w,
    ushort_t* __restrict__ wcat)
{
    const int l = blockIdx.z;
    const int n0 = blockIdx.x * 64;
    const int k0 = blockIdx.y * 64;
    const float* xw  = xproj_w + (size_t)l * D_INNER * 64;
    const float* dtw = dt_w + (size_t)l * DT_RANK * D_INNER;

    __shared__ float xs[64][33];   // [k][r]
    __shared__ float ds[32][65];   // [r][n]

    const int tid = threadIdx.x;
    {
        int row = tid >> 2;
        int col = (tid & 3) * 8;
        #pragma unroll
        for (int q = 0; q < 8; q++)
            xs[row][col + q] = xw[(size_t)(k0 + row) * 64 + col + q];
    }
    {
        int row = tid >> 3;
        int col = (tid & 7) * 8;
        #pragma unroll
        for (int q = 0; q < 8; q++)
            ds[row][col + q] = dtw[(size_t)row * D_INNER + n0 + col + q];
    }
    __syncthreads();

    const int ty = tid & 15;
    const int tx = tid >> 4;
    float acc[4][4] = {};
    #pragma unroll
    for (int r = 0; r < 32; r++) {
        float a[4], b[4];
        #pragma unroll
        for (int i = 0; i < 4; i++) a[i] = xs[ty * 4 + i][r];
        #pragma unroll
        for (int j = 0; j < 4; j++) b[j] = ds[r][tx * 4 + j];
        #pragma unroll
        for (int j = 0; j < 4; j++)
            #pragma unroll
            for (int i = 0; i < 4; i++)
                acc[j][i] = fmaf(a[i], b[j], acc[j][i]);
    }
    #pragma unroll
    for (int j = 0; j < 4; j++) {
        int n = n0 + tx * 4 + j;
        ushort4 o;
        o.x = f2bf(acc[j][0]); o.y = f2bf(acc[j][1]);
        o.z = f2bf(acc[j][2]); o.w = f2bf(acc[j][3]);
        *(ushort4*)&wcat[((size_t)l * NCAT + n) * D_INNER + k0 + ty * 4] = o;
    }
}

// ---------------------------------------------------------------------------
// build_wbc: Wcat rows 1024..1151: j<32 -> xw[k][32+j] cast; else zero pad.
// (Pad MUST be written every launch: d_ws is re-poisoned to 0xAA.)
// ---------------------------------------------------------------------------
__global__ __launch_bounds__(256) void build_wbc_kernel(
    const float* __restrict__ xproj_w, ushort_t* __restrict__ wcat)
{
    const int idx = blockIdx.x * 256 + threadIdx.x;
    const int k = idx & 1023;
    const int j = (idx >> 10) & 127;
    const int l = idx >> 17;
    ushort_t v = 0;
    if (j < 32)
        v = f2bf(xproj_w[((size_t)l * D_INNER + k) * 64 + 32 + j]);
    wcat[((size_t)l * NCAT + 1024 + j) * D_INNER + k] = v;
}

// ---------------------------------------------------------------------------
__global__ __launch_bounds__(256) void transpose_cast_kernel(
    const float* __restrict__ in, ushort_t* __restrict__ out, int K, int N)
{
    __shared__ float tile[32][33];
    const int n0 = blockIdx.x * 32, k0 = blockIdx.y * 32;
    const int tx = threadIdx.x & 31, ty = threadIdx.x >> 5;
    #pragma unroll
    for (int i = 0; i < 4; i++)
        tile[ty + i * 8][tx] = in[(size_t)(k0 + ty + i * 8) * N + n0 + tx];
    __syncthreads();
    #pragma unroll
    for (int i = 0; i < 4; i++)
        out[(size_t)(n0 + ty + i * 8) * K + k0 + tx] = f2bf(tile[tx][ty + i * 8]);
}

// ---------------------------------------------------------------------------
__global__ __launch_bounds__(256) void cast_bf16_kernel(
    const float* __restrict__ in, ushort_t* __restrict__ out)
{
    const int i = blockIdx.x * 256 + threadIdx.x;
    out[i] = f2bf(in[i]);
}

// ---------------------------------------------------------------------------
__global__ __launch_bounds__(256) void rmsnorm_kernel(
    const float* __restrict__ x, const float* __restrict__ w,
    ushort_t* __restrict__ y)
{
    const int row = blockIdx.x;
    const float* xr = x + (size_t)row * D_MODEL;
    ushort_t* yr = y + (size_t)row * D_MODEL;
    const int tid = threadIdx.x;

    float v0 = xr[tid], v1 = xr[tid + 256];
    float ss = v0 * v0 + v1 * v1;
    #pragma unroll
    for (int off = 32; off > 0; off >>= 1) ss += __shfl_down(ss, off);

    __shared__ float wsum[4];
    __shared__ float scale_s;
    int wid = tid >> 6, lane = tid & 63;
    if (lane == 0) wsum[wid] = ss;
    __syncthreads();
    if (tid == 0) {
        float tot = wsum[0] + wsum[1] + wsum[2] + wsum[3];
        scale_s = 1.0f / sqrtf(tot / (float)D_MODEL + 1e-5f);
    }
    __syncthreads();
    float sc = scale_s;
    yr[tid] = f2bf(v0 * sc * w[tid]);
    yr[tid + 256] = f2bf(v1 * sc * w[tid + 256]);
}

// ---------------------------------------------------------------------------
// Causal dwconv (K=4) + bias + silu. Reads bf16 xz (stride 2048, xp plane),
// writes bf16 u.
// ---------------------------------------------------------------------------
__global__ __launch_bounds__(256) void conv_silu_kernel(
    const ushort_t* __restrict__ xz, const float* __restrict__ w,
    const float* __restrict__ bconv, ushort_t* __restrict__ outb)
{
    const int idx = blockIdx.x * 256 + threadIdx.x;
    const int d = idx & (D_INNER - 1);
    const int t = (idx >> 10) & (SEQ - 1);
    const int row = idx >> 10;
    const ushort_t* base = xz + (size_t)row * 2048 + d;

    float s = 0.f;
    #pragma unroll
    for (int k = 0; k < KCONV; k++) {
        int tt = t + k - (KCONV - 1);
        if (tt >= 0)
            s = fmaf(bf2f(base[(ptrdiff_t)(k - (KCONV - 1)) * 2048]), w[d * KCONV + k], s);
    }
    s += bconv[d];
    float r = s / (1.f + __expf(-s));
    outb[idx] = f2bf(r);
}

// ---------------------------------------------------------------------------
// Chunked selective scan (3 passes), CLEN=32. dt/B/C in dbl (stride NCAT):
// dbl[row][d]=softplus'ed dt; dbl[row][1024+n]=B[n]; dbl[row][1040+n]=C[n].
// u is bf16 in xb; z is bf16 in xz[:,1024:].
// ---------------------------------------------------------------------------
__global__ __launch_bounds__(256) void scan_pass1(
    const float* __restrict__ dbl, const ushort_t* __restrict__ ub,
    const float* __restrict__ A_log,
    float* __restrict__ hfin, float* __restrict__ sumdt)
{
    const int tid = threadIdx.x;
    const int b = blockIdx.x >> 7;
    const int p = (blockIdx.x >> 2) & 31;
    const int d = ((blockIdx.x & 3) << 8) + tid;
    const int t0 = p * CLEN;

    float A[D_STATE];
    #pragma unroll
    for (int n = 0; n < D_STATE; n++) A[n] = -expf(A_log[d * D_STATE + n]);

    float h[D_STATE] = {};
    float sdt = 0.f;

    const float* dtp = dbl + ((size_t)b * SEQ + t0) * NCAT + d;
    const float* bp  = dbl + ((size_t)b * SEQ + t0) * NCAT + 1024;
    const ushort_t* up = ub + ((size_t)b * SEQ + t0) * D_INNER + d;

    for (int t = 0; t < CLEN; t++) {
        float dtv = dtp[(size_t)t * NCAT];
        float uv  = bf2f(up[(size_t)t * D_INNER]);
        float dtu = dtv * uv;
        sdt += dtv;
        #pragma unroll
        for (int n = 0; n < D_STATE; n++)
            h[n] = fmaf(__expf(dtv * A[n]), h[n], dtu * bp[t * NCAT + n]);
    }

    size_t base = (size_t)(b * PCH + p) * D_STATE * D_INNER + d;
    #pragma unroll
    for (int n = 0; n < D_STATE; n++) hfin[base + (size_t)n * D_INNER] = h[n];
    sumdt[(size_t)(b * PCH + p) * D_INNER + d] = sdt;
}

__global__ __launch_bounds__(256) void scan_pass2(
    const float* __restrict__ A_log, const float* __restrict__ sumdt,
    float* __restrict__ hc)
{
    const int tid = threadIdx.x;
    const int b = blockIdx.x >> 6;
    const int n = (blockIdx.x >> 2) & 15;
    const int d = ((blockIdx.x & 3) << 8) + tid;

    const float Aval = -expf(A_log[d * D_STATE + n]);
    float h = 0.f;
    for (int p = 0; p < PCH; p++) {
        size_t idx = ((size_t)(b * PCH + p) * D_STATE + n) * D_INNER + d;
        float fin = hc[idx];
        hc[idx] = h;
        h = fmaf(__expf(Aval * sumdt[(size_t)(b * PCH + p) * D_INNER + d]), h, fin);
    }
}

// pass3: u (bf16, in ub) read then overwritten IN PLACE with y*silu(z).
__global__ __launch_bounds__(256) void scan_pass3(
    const float* __restrict__ dbl, const ushort_t* __restrict__ xz,
    const float* __restrict__ A_log, const float* __restrict__ Dp,
    const float* __restrict__ hstart, ushort_t* ub)
{
    const int tid = threadIdx.x;
    const int b = blockIdx.x >> 7;
    const int p = (blockIdx.x >> 2) & 31;
    const int d = ((blockIdx.x & 3) << 8) + tid;
    const int t0 = p * CLEN;

    float A[D_STATE];
    #pragma unroll
    for (int n = 0; n < D_STATE; n++) A[n] = -expf(A_log[d * D_STATE + n]);
    const float Dv = Dp[d];

    float h[D_STATE];
    size_t base = (size_t)(b * PCH + p) * D_STATE * D_INNER + d;
    #pragma unroll
    for (int n = 0; n < D_STATE; n++) h[n] = hstart[base + (size_t)n * D_INNER];

    const float* dtp = dbl + ((size_t)b * SEQ + t0) * NCAT + d;
    const float* bp  = dbl + ((size_t)b * SEQ + t0) * NCAT + 1024;
    const ushort_t* zp = xz + ((size_t)b * SEQ + t0) * 2048 + 1024 + d;
    ushort_t* up = ub + ((size_t)b * SEQ + t0) * D_INNER + d;

    for (int t = 0; t < CLEN; t++) {
        float dtv = dtp[(size_t)t * NCAT];
        float uv  = bf2f(up[(size_t)t * D_INNER]);
        float zv  = bf2f(zp[(size_t)t * 2048]);
        float dtu = dtv * uv;
        float y = 0.f;
        #pragma unroll
        for (int n = 0; n < D_STATE; n++) {
            h[n] = fmaf(__expf(dtv * A[n]), h[n], dtu * bp[t * NCAT + n]);
            y = fmaf(h[n], bp[t * NCAT + 16 + n], y);
        }
        float res = fmaf(uv, Dv, y);
        res *= zv / (1.f + __expf(-zv));
        up[(size_t)t * D_INNER] = f2bf(res);
    }
}

// ---------------------------------------------------------------------------
__global__ __launch_bounds__(256) void softmax_kernel(
    const float* __restrict__ in, float* __restrict__ out)
{
    const int idx = blockIdx.x * 256 + threadIdx.x;
    float v = in[idx];
    float m = v;
    #pragma unroll
    for (int off = 16; off > 0; off >>= 1) m = fmaxf(m, __shfl_xor(m, off, 32));
    float e = expf(v - m);
    float s = e;
    #pragma unroll
    for (int off = 16; off > 0; off >>= 1) s += __shfl_xor(s, off, 32);
    out[idx] = e / s;
}

// ---------------------------------------------------------------------------
extern "C" void kernel_launch(void* const* d_in, const int* in_sizes, int n_in,
                              void* d_out, int out_size, void* d_ws, size_t ws_size,
                              hipStream_t stream)
{
    const float* x       = (const float*)d_in[0];
    const float* lin1_w  = (const float*)d_in[1];
    const float* lin1_b  = (const float*)d_in[2];
    const float* norm_w  = (const float*)d_in[3];
    const float* in_w    = (const float*)d_in[4];
    const float* conv_w  = (const float*)d_in[5];
    const float* conv_b  = (const float*)d_in[6];
    const float* xproj_w = (const float*)d_in[7];
    const float* dt_w    = (const float*)d_in[8];
    const float* dt_b    = (const float*)d_in[9];
    const float* A_log   = (const float*)d_in[10];
    const float* Dp      = (const float*)d_in[11];
    const float* out_w   = (const float*)d_in[12];
    const float* lin2_w  = (const float*)d_in[13];
    const float* lin2_b  = (const float*)d_in[14];
    float* outp = (float*)d_out;
    (void)ws_size; (void)in_sizes; (void)n_in; (void)out_size;

    float* ws = (float*)d_ws;
    const size_t F1M = 1u << 20;
    float* h     = ws;                        // 2M fl
    float* dbl   = h + 2 * F1M;               // 4.5M fl (also lin2 logits)
    float* sumdt = dbl + (size_t)NTOK * NCAT; // 128K fl
    float* hfin  = sumdt + (size_t)BATCH * PCH * D_INNER; // 2M fl
    ushort_t* xzb   = (ushort_t*)(hfin + 2 * F1M);        // 8M us (xp|z, 2048)
    ushort_t* hn_bf = xzb + 8 * F1M;                      // 2M us
    ushort_t* xb    = hn_bf + 2 * F1M;                    // 4M us
    ushort_t* lin1_wt = xb + 4 * F1M;                     // 512*1024
    ushort_t* in_wt   = lin1_wt + (size_t)512 * 1024;     // 4*2048*512
    ushort_t* out_wt  = in_wt + (size_t)4 * 2048 * 512;   // 4*512*1024
    ushort_t* lin2_wt = out_wt + (size_t)4 * 512 * 1024;  // 1024*512
    ushort_t* wcat    = lin2_wt + (size_t)1024 * 512;     // 4*1152*1024

    dim3 blk(256);

    // --- weight prep ---
    transpose_cast_kernel<<<dim3(512 / 32, 1024 / 32), blk, 0, stream>>>(
        lin1_w, lin1_wt, LATENT, D_MODEL);
    for (int l = 0; l < N_LAYERS; l++) {
        transpose_cast_kernel<<<dim3(2048 / 32, 512 / 32), blk, 0, stream>>>(
            in_w + (size_t)l * 512 * 2048, in_wt + (size_t)l * 2048 * 512, 512, 2048);
        transpose_cast_kernel<<<dim3(512 / 32, 1024 / 32), blk, 0, stream>>>(
            out_w + (size_t)l * 1024 * 512, out_wt + (size_t)l * 512 * 1024, 1024, 512);
    }
    transpose_cast_kernel<<<dim3(1024 / 32, 512 / 32), blk, 0, stream>>>(
        lin2_w, lin2_wt, D_MODEL, LATENT);
    build_wdt_kernel<<<dim3(16, 16, N_LAYERS), blk, 0, stream>>>(
        xproj_w, dt_w, wcat);
    build_wbc_kernel<<<dim3((N_LAYERS * 128 * 1024) / 256), blk, 0, stream>>>(
        xproj_w, wcat);

    // x -> bf16
    cast_bf16_kernel<<<dim3((NTOK * LATENT) / 256), blk, 0, stream>>>(x, xb);

    // lin1: h = x_bf @ lin1_wt^T + b  (fp32 out, 8x64=512 blocks)
    gemm_bf16_tile<<<dim3(D_MODEL / 64, NTOK / 64), blk, 0, stream>>>(
        xb, LATENT, lin1_wt, LATENT, h, nullptr, D_MODEL, lin1_b,
        NTOK, D_MODEL, LATENT, 1);

    for (int l = 0; l < N_LAYERS; l++) {
        const float* nw = norm_w + (size_t)l * D_MODEL;
        const float* cw = conv_w + (size_t)l * D_INNER * KCONV;
        const float* cb = conv_b + (size_t)l * D_INNER;
        const float* db = dt_b + (size_t)l * D_INNER;
        const float* al = A_log + (size_t)l * D_INNER * D_STATE;
        const float* dp = Dp + (size_t)l * D_INNER;
        const ushort_t* iwt = in_wt + (size_t)l * 2048 * 512;
        const ushort_t* owt = out_wt + (size_t)l * 512 * 1024;
        const ushort_t* wc  = wcat + (size_t)l * NCAT * D_INNER;

        rmsnorm_kernel<<<dim3(NTOK), blk, 0, stream>>>(h, nw, hn_bf);

        // fused in-proj: xzb = hn @ in_w[l]  (N=2048, bf16 out, 32x64=2048 blocks)
        gemm_bf16_tile<<<dim3(2048 / 64, NTOK / 64), blk, 0, stream>>>(
            hn_bf, D_MODEL, iwt, D_MODEL, nullptr, xzb, 2048, nullptr,
            NTOK, 2048, D_MODEL, 8);

        // conv + silu: xzb[:, :1024] -> xb (bf16 u)
        conv_silu_kernel<<<dim3((NTOK * D_INNER) / 256), blk, 0, stream>>>(
            xzb, cw, cb, xb);

        // merged xproj+dt GEMM: dbl[:, :1024]=softplus(u@Wdt+dt_b),
        //                       dbl[:, 1024:1056]=B|C   (fp32 out, 18x64=1152 blocks)
        gemm_bf16_tile<<<dim3(NCAT / 64, NTOK / 64), blk, 0, stream>>>(
            xb, D_INNER, wc, D_INNER, dbl, nullptr, NCAT, db,
            NTOK, NCAT, D_INNER, 4);

        // chunked scan; pass3 overwrites xb in place with y*silu(z)
        scan_pass1<<<dim3(BATCH * PCH * (D_INNER / 256)), blk, 0, stream>>>(
            dbl, xb, al, hfin, sumdt);
        scan_pass2<<<dim3(BATCH * D_STATE * (D_INNER / 256)), blk, 0, stream>>>(
            al, sumdt, hfin);
        scan_pass3<<<dim3(BATCH * PCH * (D_INNER / 256)), blk, 0, stream>>>(
            dbl, xzb, al, dp, hfin, xb);

        // h += y_bf @ out_wt^T  (fp32 accumulate, 8x64=512 blocks)
        gemm_bf16_tile<<<dim3(D_MODEL / 64, NTOK / 64), blk, 0, stream>>>(
            xb, D_INNER, owt, D_INNER, h, nullptr, D_MODEL, nullptr,
            NTOK, D_MODEL, D_INNER, 2);
    }

    // h -> bf16, lin2 (logits into dbl), softmax
    cast_bf16_kernel<<<dim3((NTOK * D_MODEL) / 256), blk, 0, stream>>>(h, xb);
    gemm_bf16_tile<<<dim3(LATENT / 64, NTOK / 64), blk, 0, stream>>>(
        xb, D_MODEL, lin2_wt, D_MODEL, dbl, nullptr, LATENT, lin2_b,
        NTOK, LATENT, D_MODEL, 1);
    softmax_kernel<<<dim3((NTOK * LATENT) / 256), blk, 0, stream>>>(dbl, outp);
}